// Round 15
// baseline (27.401 us; speedup 1.0000x reference)
//
#include <hip/hip_runtime.h>

#define NB   8192
#define NJ   14
#define NC   18
#define PIX  196            // 14*14
#define CHE  (NC * PIX)     // 3528 floats per batch
#define CHB  (PIX * 4)      // 784 bytes per channel image
#define BPB  8              // batches per block (1 wave = 1 batch)
#define NBLK (NB / BPB)     // 1024 blocks
#define GSTR 16             // padded row stride; cols 14,15 replicate cols 0,1
#define ZROW 14             // zero row (unused position slots)

#define WSUM_INV 0.398943491f   // 1 / sum(exp(-k^2/2), k=-4..4)

struct Chunk {                      // static-indexed register double-buffer
    float4 hv[4];
    float  inv[4];
    int    syo[4], sxo[4];
};

__global__ __launch_bounds__(512, 6) void mse_partial_kernel(
    const float* __restrict__ h, const float* __restrict__ t,
    const int* __restrict__ v, float2* __restrict__ partials)
{
    __shared__ float  gs[15 * GSTR];   // g[p][r]; rows 0..13 table, row 14 zeros
    __shared__ float  gmx[14];         // per-position row max (min is identically 0)
    __shared__ int    scode[BPB * 16]; // per-wave joint codes
    __shared__ float2 list[BPB * NC];  // {inv, pos_bits | ch<<24}
    __shared__ float  wvs[BPB];
    __shared__ float  wred[BPB];

    const int tid = threadIdx.x;
    const int b0  = blockIdx.x * BPB;
    const int w   = tid >> 6, lane = tid & 63;
    const int b   = b0 + w;

    // ---- phase 0: padded g table (cols 14,15 = wrap copy of cols 0,1) ----
    if (tid < 15 * GSTR) {
        int p = tid >> 4, r = tid & 15;
        int rc = (r < 14) ? r : (r - 14);          // wrap pad
        float val = 0.f;
        if (p < 14) {
            const float wl[9] = {0.00033546262f, 0.011108997f, 0.13533528f, 0.60653066f,
                                 1.0f, 0.60653066f, 0.13533528f, 0.011108997f, 0.00033546262f};
            float acc = 0.f;
            #pragma unroll
            for (int k = 0; k < 9; k++) {
                int m  = rc + k - 4;
                int sm = m < 0 ? (-m - 1) : (m > 13 ? 27 - m : m);  // symmetric reflect
                if (sm == p) acc += wl[k];
            }
            val = acc * WSUM_INV;
        }
        gs[tid] = val;                              // row 14 stays zero
    }
    __syncthreads();
    if (tid < 14) {
        float mx = 0.f;
        #pragma unroll
        for (int r = 0; r < 14; r++) mx = fmaxf(mx, gs[tid * GSTR + r]);
        gmx[tid] = mx;
    }
    __syncthreads();

    // per-lane byte offsets for the 196-pixel group max eval
    int rb_[4], cb_[4];
    #pragma unroll
    for (int q = 0; q < 4; q++) {
        int e = lane + 64 * q;
        int ee = (e < PIX) ? e : PIX - 1;          // dup pixel is fine for max
        int rr = ee / 14, cc = ee - 14 * rr;
        rb_[q] = rr << 2; cb_[q] = cc << 2;
    }

    // ---- phase 1: per-wave (= per-batch) channel metadata ----
    int xi = 0, yi = 0, vis = 0, vy = 0;
    if (lane < NJ) {
        float2 tv = ((const float2*)t)[b * NJ + lane];   // {x, y}
        int2   vv = ((const int2*)v)[b * NJ + lane];
        xi = (int)(tv.x * 14.0f); xi = xi < 0 ? 0 : (xi > 13 ? 13 : xi);
        yi = (int)(tv.y * 14.0f); yi = yi < 0 ? 0 : (yi > 13 ? 13 : yi);
        vis = (vv.x == 1); vy = (vv.y == 1);
    }
    if (lane < NJ) scode[w * 16 + lane] = (vis << 8) | (xi << 4) | yi;
    {
        unsigned long long bx = __ballot(lane < NJ && vis);
        unsigned long long by = __ballot(lane < NJ && vy);
        if (lane == 0) wvs[w] = (float)(__popcll(bx) + __popcll(by));
    }

    float inv_c = 0.f;
    int   pos_c = 0, act_c = 0, np_c = 0;
    if (lane < NJ && vis) {
        inv_c = 1.f / (gmx[yi] * gmx[xi]);          // mn == 0 identically
        act_c = 1; np_c = 1;
        pos_c = yi | (xi << 4) | (ZROW << 8) | (ZROW << 16);
    }
    for (int gi = 0; gi < 4; gi++) {
        int c0  = __builtin_amdgcn_readfirstlane(scode[w * 16 + 3 * gi]);
        int c1_ = __builtin_amdgcn_readfirstlane(scode[w * 16 + 3 * gi + 1]);
        int c2  = __builtin_amdgcn_readfirstlane(scode[w * 16 + 3 * gi + 2]);
        int packed = 0, np = 0;                     // pure SALU from here
        if (c0 & 0x100) { packed = c0 & 0xFF; np = 1; }
        if (c1_ & 0x100) {
            int pc = c1_ & 0xFF;
            bool dup = (np > 0) && ((packed & 0xFF) == pc);
            if (!dup) { packed |= pc << (8 * np); np++; }
        }
        if (c2 & 0x100) {
            int pc = c2 & 0xFF;
            bool dup = false;
            for (int s = 0; s < np; s++) if (((packed >> (8 * s)) & 0xFF) == pc) dup = true;
            if (!dup) { packed |= pc << (8 * np); np++; }
        }
        int pp = packed;
        if (np < 2) pp |= ZROW << 8;
        if (np < 3) pp |= ZROW << 16;

        float mx = 1.f;
        if (np == 1) {
            int y = packed & 15, x = (packed >> 4) & 15;
            mx = gmx[y] * gmx[x];
        } else if (np >= 2) {            // wave-uniform: exact 196-pixel MAX only
            const int o0 = ( pp        & 15) << 6, p0 = ((pp >> 4)  & 15) << 6;
            const int o1 = ((pp >> 8)  & 15) << 6, p1 = ((pp >> 12) & 15) << 6;
            const int o2 = ((pp >> 16) & 15) << 6, p2 = ((pp >> 20) & 15) << 6;
            const char* g8 = (const char*)gs;
            float lmx = 0.f;
            #pragma unroll
            for (int q2 = 0; q2 < 4; q2++) {
                float f = *(const float*)(g8 + o0 + rb_[q2]) * *(const float*)(g8 + p0 + cb_[q2])
                        + *(const float*)(g8 + o1 + rb_[q2]) * *(const float*)(g8 + p1 + cb_[q2])
                        + *(const float*)(g8 + o2 + rb_[q2]) * *(const float*)(g8 + p2 + cb_[q2]);
                lmx = fmaxf(lmx, f);
            }
            #pragma unroll
            for (int m = 1; m < 64; m <<= 1)
                lmx = fmaxf(lmx, __shfl_xor(lmx, m));
            mx = lmx;
        }
        if (lane == NJ + gi && np > 0) {
            inv_c = 1.f / mx; act_c = 1; np_c = np;
            pos_c = pp;
        }
    }
    // partition this wave's entries: [0,c1) single-pos, [c1,cT) multi-pos
    unsigned long long b1 = __ballot(act_c && np_c == 1);
    unsigned long long bX = __ballot(act_c && np_c >= 2);
    const int c1 = __popcll(b1);
    const int cT = c1 + __popcll(bX);
    unsigned long long below = (1ull << lane) - 1ull;
    if (act_c) {
        int idx = (np_c == 1) ? __popcll(b1 & below) : c1 + __popcll(bX & below);
        float2 e;
        e.x = inv_c;
        e.y = __int_as_float(pos_c | (lane << 24));   // channel == lane
        list[w * NC + idx] = e;
    }
    // no barrier: each wave reads only its own list segment (in-order LDS)

    // ---- phase 2: software-pipelined fast path (2 chunks in flight) ----
    const char* hb   = (const char*)(h + (size_t)b * CHE);
    const int  lane49 = lane < 48 ? lane : 48;
    const bool lv     = (lane < 49);
    const int  pix0   = lane49 * 4;
    const int  rr0    = pix0 / 14;
    const int  cc0    = pix0 - 14 * rr0;       // even: 0..12
    const bool wrap   = (cc0 == 12);
    const int  voff   = lane49 * 16;
    const int  brr = rr0 << 2, bcc = cc0 << 2;
    const int  lbase  = w * NC;
    const char* g8 = (const char*)gs;
    float acc = 0.f;

    Chunk cA, cB;

    auto STAGE = [&](Chunk& C, int base4) {    // read meta + issue 4 loads
        #pragma unroll
        for (int u = 0; u < 4; u++) {
            int ee = base4 + u;
            ee = (ee < c1) ? ee : c1 - 1;      // dup tail -> cache hits
            float2 mv = list[lbase + ee];
            C.inv[u] = mv.x;
            int sp = __builtin_amdgcn_readfirstlane(__float_as_int(mv.y));
            C.syo[u] = ( sp       & 15) << 6;
            C.sxo[u] = ((sp >> 4) & 15) << 6;
            int sb = (sp >> 24) * CHB;         // SALU mul
            C.hv[u] = *(const float4*)(hb + sb + voff);
        }
    };
    auto COMP = [&](Chunk& C, int base4) {     // consume 4 entries
        #pragma unroll
        for (int u = 0; u < 4; u++) {
            const float* ry = (const float*)(g8 + C.syo[u] + brr);
            const char*  rx = g8 + C.sxo[u] + bcc;
            float2 xA = *(const float2*)rx;            // ds_read2_b64
            float2 xB = *(const float2*)(rx + 8);
            float wy0 = ry[0], wy1 = ry[1];            // ds_read2_b32
            float wy0i = wy0 * C.inv[u];
            float wyCi = (wrap ? wy1 : wy0) * C.inv[u];
            float d0 = fmaf(-wy0i, xA.x, C.hv[u].x);
            float d1 = fmaf(-wy0i, xA.y, C.hv[u].y);
            float d2 = fmaf(-wyCi, xB.x, C.hv[u].z);
            float d3 = fmaf(-wyCi, xB.y, C.hv[u].w);
            float s  = fmaf(d0, d0, fmaf(d1, d1, fmaf(d2, d2, d3 * d3)));
            acc += (base4 + u < c1) ? s : 0.f;
        }
    };

    const int nch = (c1 + 3) >> 2;             // <= 5 (c1 <= 18)
    if (nch > 0) STAGE(cA, 0);                 // fully-static 2-deep schedule
    if (nch > 1) STAGE(cB, 4);
    if (nch > 0) COMP (cA, 0);
    if (nch > 2) STAGE(cA, 8);
    if (nch > 1) COMP (cB, 4);
    if (nch > 3) STAGE(cB, 12);
    if (nch > 2) COMP (cA, 8);
    if (nch > 4) STAGE(cA, 16);
    if (nch > 3) COMP (cB, 12);
    if (nch > 4) COMP (cA, 16);

    // slow path: np >= 2 (avg ~2 entries)
    for (int e = c1; e < cT; e++) {
        float2 mv = list[lbase + e];
        float inv = mv.x;
        int sp = __builtin_amdgcn_readfirstlane(__float_as_int(mv.y));
        int sb = (sp >> 24) * CHB;
        float4 hv = *(const float4*)(hb + sb + voff);
        float f0 = 0.f, f1 = 0.f, f2 = 0.f, f3 = 0.f;
        #pragma unroll
        for (int q = 0; q < 3; q++) {
            int yo = ((sp >> (8 * q))     & 15) << 6;
            int xo = ((sp >> (8 * q + 4)) & 15) << 6;
            const float* ry = (const float*)(g8 + yo + brr);
            const char*  rx = g8 + xo + bcc;
            float2 xA = *(const float2*)rx;
            float2 xB = *(const float2*)(rx + 8);
            float wy0 = ry[0], wy1 = ry[1];
            float wyC = wrap ? wy1 : wy0;
            f0 = fmaf(wy0, xA.x, f0);
            f1 = fmaf(wy0, xA.y, f1);
            f2 = fmaf(wyC, xB.x, f2);
            f3 = fmaf(wyC, xB.y, f3);
        }
        float d0 = fmaf(-f0, inv, hv.x);
        float d1 = fmaf(-f1, inv, hv.y);
        float d2 = fmaf(-f2, inv, hv.z);
        float d3 = fmaf(-f3, inv, hv.w);
        acc += fmaf(d0, d0, fmaf(d1, d1, fmaf(d2, d2, d3 * d3)));
    }

    acc = lv ? acc : 0.f;            // single lane-mask application

    // ---- reduce ----
    #pragma unroll
    for (int off = 32; off > 0; off >>= 1) acc += __shfl_down(acc, off);
    if (lane == 0) wred[w] = acc;
    __syncthreads();
    if (tid == 0) {
        float2 pr;
        float s = 0.f, vs = 0.f;
        #pragma unroll
        for (int q = 0; q < BPB; q++) { s += wred[q]; vs += wvs[q]; }
        pr.x = s; pr.y = vs;
        partials[blockIdx.x] = pr;
    }
}

__global__ __launch_bounds__(512) void finalize_kernel(
    const float4* __restrict__ partials4, float* __restrict__ out)
{
    __shared__ float w1[8], w2[8];
    int tid = threadIdx.x;
    float4 p = partials4[tid];          // 512 float4 == 1024 float2 partials
    float s = p.x + p.z, vs = p.y + p.w;
    #pragma unroll
    for (int off = 32; off > 0; off >>= 1) {
        s  += __shfl_down(s, off);
        vs += __shfl_down(vs, off);
    }
    if ((tid & 63) == 0) { w1[tid >> 6] = s; w2[tid >> 6] = vs; }
    __syncthreads();
    if (tid == 0) {
        float stot = 0.f, vtot = 0.f;
        #pragma unroll
        for (int q = 0; q < 8; q++) { stot += w1[q]; vtot += w2[q]; }
        out[0] = stot / (vtot * 0.5f);
    }
}

extern "C" void kernel_launch(void* const* d_in, const int* in_sizes, int n_in,
                              void* d_out, int out_size, void* d_ws, size_t ws_size,
                              hipStream_t stream) {
    // inputs: 0=os (UNUSED), 1=h [B,18,14,14] f32, 2=t [B,14,2] f32, 3=v [B,14,2] i32
    const float* h = (const float*)d_in[1];
    const float* t = (const float*)d_in[2];
    const int*   v = (const int*)d_in[3];
    float2* partials = (float2*)d_ws;   // NBLK float2

    mse_partial_kernel<<<NBLK, 512, 0, stream>>>(h, t, v, partials);
    finalize_kernel<<<1, 512, 0, stream>>>((const float4*)partials, (float*)d_out);
}

// Round 16
// 21.539 us; speedup vs baseline: 1.2721x; 1.2721x over previous
//
#include <hip/hip_runtime.h>

#define NB   8192
#define NJ   14
#define NC   18
#define PIX  196            // 14*14
#define CHE  (NC * PIX)     // 3528 floats per batch
#define CHB  (PIX * 4)      // 784 bytes per channel image
#define BPB  8              // batches per block (1 wave = 1 batch)
#define NBLK (NB / BPB)     // 1024 blocks
#define GSTR 16             // padded row stride; cols 14,15 replicate cols 0,1
#define ZROW 14             // zero row (unused position slots)

#define WSUM_INV 0.398943491f   // 1 / sum(exp(-k^2/2), k=-4..4)

__global__ __launch_bounds__(512, 8) void mse_partial_kernel(
    const float* __restrict__ h, const float* __restrict__ t,
    const int* __restrict__ v, float2* __restrict__ partials)
{
    __shared__ float  gs[15 * GSTR];   // g[p][r]; rows 0..13 table, row 14 zeros
    __shared__ float  gmx[14];         // per-position row max (min is identically 0)
    __shared__ int    scode[BPB * 16]; // per-wave joint codes
    __shared__ float2 list[BPB * NC];  // {inv, pos_bits | ch<<24}
    __shared__ float  wvs[BPB];
    __shared__ float  wred[BPB];

    const int tid = threadIdx.x;
    const int b0  = blockIdx.x * BPB;
    const int w   = tid >> 6, lane = tid & 63;
    const int b   = b0 + w;

    // ---- phase 0: padded g table (cols 14,15 = wrap copy of cols 0,1) ----
    if (tid < 15 * GSTR) {
        int p = tid >> 4, r = tid & 15;
        int rc = (r < 14) ? r : (r - 14);          // wrap pad
        float val = 0.f;
        if (p < 14) {
            const float wl[9] = {0.00033546262f, 0.011108997f, 0.13533528f, 0.60653066f,
                                 1.0f, 0.60653066f, 0.13533528f, 0.011108997f, 0.00033546262f};
            float acc = 0.f;
            #pragma unroll
            for (int k = 0; k < 9; k++) {
                int m  = rc + k - 4;
                int sm = m < 0 ? (-m - 1) : (m > 13 ? 27 - m : m);  // symmetric reflect
                if (sm == p) acc += wl[k];
            }
            val = acc * WSUM_INV;
        }
        gs[tid] = val;                              // row 14 stays zero
    }
    __syncthreads();
    if (tid < 14) {
        float mx = 0.f;
        #pragma unroll
        for (int r = 0; r < 14; r++) mx = fmaxf(mx, gs[tid * GSTR + r]);
        gmx[tid] = mx;
    }
    __syncthreads();

    // per-lane byte offsets for the 196-pixel group max eval
    int rb_[4], cb_[4];
    #pragma unroll
    for (int q = 0; q < 4; q++) {
        int e = lane + 64 * q;
        int ee = (e < PIX) ? e : PIX - 1;          // dup pixel is fine for max
        int rr = ee / 14, cc = ee - 14 * rr;
        rb_[q] = rr << 2; cb_[q] = cc << 2;
    }

    // ---- phase 1: per-wave (= per-batch) channel metadata ----
    int xi = 0, yi = 0, vis = 0, vy = 0;
    if (lane < NJ) {
        float2 tv = ((const float2*)t)[b * NJ + lane];   // {x, y}
        int2   vv = ((const int2*)v)[b * NJ + lane];
        xi = (int)(tv.x * 14.0f); xi = xi < 0 ? 0 : (xi > 13 ? 13 : xi);
        yi = (int)(tv.y * 14.0f); yi = yi < 0 ? 0 : (yi > 13 ? 13 : yi);
        vis = (vv.x == 1); vy = (vv.y == 1);
    }
    if (lane < NJ) scode[w * 16 + lane] = (vis << 8) | (xi << 4) | yi;
    {
        unsigned long long bx = __ballot(lane < NJ && vis);
        unsigned long long by = __ballot(lane < NJ && vy);
        if (lane == 0) wvs[w] = (float)(__popcll(bx) + __popcll(by));
    }

    float inv_c = 0.f;
    int   pos_c = 0, act_c = 0, np_c = 0;
    if (lane < NJ && vis) {
        inv_c = 1.f / (gmx[yi] * gmx[xi]);          // mn == 0 identically
        act_c = 1; np_c = 1;
        pos_c = yi | (xi << 4) | (ZROW << 8) | (ZROW << 16);
    }
    for (int gi = 0; gi < 4; gi++) {
        int c0  = __builtin_amdgcn_readfirstlane(scode[w * 16 + 3 * gi]);
        int c1_ = __builtin_amdgcn_readfirstlane(scode[w * 16 + 3 * gi + 1]);
        int c2  = __builtin_amdgcn_readfirstlane(scode[w * 16 + 3 * gi + 2]);
        int packed = 0, np = 0;                     // pure SALU from here
        if (c0 & 0x100) { packed = c0 & 0xFF; np = 1; }
        if (c1_ & 0x100) {
            int pc = c1_ & 0xFF;
            bool dup = (np > 0) && ((packed & 0xFF) == pc);
            if (!dup) { packed |= pc << (8 * np); np++; }
        }
        if (c2 & 0x100) {
            int pc = c2 & 0xFF;
            bool dup = false;
            for (int s = 0; s < np; s++) if (((packed >> (8 * s)) & 0xFF) == pc) dup = true;
            if (!dup) { packed |= pc << (8 * np); np++; }
        }
        int pp = packed;
        if (np < 2) pp |= ZROW << 8;
        if (np < 3) pp |= ZROW << 16;

        float mx = 1.f;
        if (np == 1) {
            int y = packed & 15, x = (packed >> 4) & 15;
            mx = gmx[y] * gmx[x];
        } else if (np >= 2) {            // wave-uniform: exact 196-pixel MAX only
            const int o0 = ( pp        & 15) << 6, p0 = ((pp >> 4)  & 15) << 6;
            const int o1 = ((pp >> 8)  & 15) << 6, p1 = ((pp >> 12) & 15) << 6;
            const int o2 = ((pp >> 16) & 15) << 6, p2 = ((pp >> 20) & 15) << 6;
            const char* g8 = (const char*)gs;
            float lmx = 0.f;
            #pragma unroll
            for (int q2 = 0; q2 < 4; q2++) {
                float f = *(const float*)(g8 + o0 + rb_[q2]) * *(const float*)(g8 + p0 + cb_[q2])
                        + *(const float*)(g8 + o1 + rb_[q2]) * *(const float*)(g8 + p1 + cb_[q2])
                        + *(const float*)(g8 + o2 + rb_[q2]) * *(const float*)(g8 + p2 + cb_[q2]);
                lmx = fmaxf(lmx, f);
            }
            #pragma unroll
            for (int m = 1; m < 64; m <<= 1)
                lmx = fmaxf(lmx, __shfl_xor(lmx, m));
            mx = lmx;
        }
        if (lane == NJ + gi && np > 0) {
            inv_c = 1.f / mx; act_c = 1; np_c = np;
            pos_c = pp;
        }
    }
    // partition this wave's entries: [0,c1) single-pos, [c1,cT) multi-pos
    unsigned long long b1 = __ballot(act_c && np_c == 1);
    unsigned long long bX = __ballot(act_c && np_c >= 2);
    const int c1 = __popcll(b1);
    const int cT = c1 + __popcll(bX);
    unsigned long long below = (1ull << lane) - 1ull;
    if (act_c) {
        int idx = (np_c == 1) ? __popcll(b1 & below) : c1 + __popcll(bX & below);
        float2 e;
        e.x = inv_c;
        e.y = __int_as_float(pos_c | (lane << 24));   // channel == lane
        list[w * NC + idx] = e;
    }
    // no barrier: each wave reads only its own list segment (in-order LDS)

    // ---- phase 2: stream h; scalar meta; neg-fma per pixel ----
    const char* hb   = (const char*)(h + (size_t)b * CHE);
    const int  lane49 = lane < 48 ? lane : 48;
    const bool lv     = (lane < 49);
    const int  pix0   = lane49 * 4;
    const int  rr0    = pix0 / 14;
    const int  cc0    = pix0 - 14 * rr0;       // even: 0..12
    const bool wrap   = (cc0 == 12);
    const int  voff   = lane49 * 16;
    const int  brr = rr0 << 2, bcc = cc0 << 2;
    const int  lbase  = w * NC;
    const char* g8 = (const char*)gs;
    float acc = 0.f;

    // fast path: np == 1, full chunks of 4 (no masks)
    const int nfull = c1 & ~3;
    for (int base = 0; base < nfull; base += 4) {
        float inv[4];
        int   syo[4], sxo[4], sb[4];
        float4 hv[4];
        #pragma unroll
        for (int u = 0; u < 4; u++) {
            float2 mv = list[lbase + base + u];
            inv[u] = mv.x;
            int sp = __builtin_amdgcn_readfirstlane(__float_as_int(mv.y));
            syo[u] = ( sp       & 15) << 6;
            sxo[u] = ((sp >> 4) & 15) << 6;
            sb[u]  = (sp >> 24) * CHB;                 // SALU mul
            hv[u] = *(const float4*)(hb + sb[u] + voff);
        }
        #pragma unroll
        for (int u = 0; u < 4; u++) {
            const float* ry = (const float*)(g8 + syo[u] + brr);
            const char*  rx = g8 + sxo[u] + bcc;
            float2 xA = *(const float2*)rx;            // ds_read2_b64 pair
            float2 xB = *(const float2*)(rx + 8);
            float wy0 = ry[0], wy1 = ry[1];            // ds_read2_b32
            float wy0i = wy0 * inv[u];
            float wyCi = (wrap ? wy1 : wy0) * inv[u];
            float d0 = fmaf(-wy0i, xA.x, hv[u].x);
            float d1 = fmaf(-wy0i, xA.y, hv[u].y);
            float d2 = fmaf(-wyCi, xB.x, hv[u].z);
            float d3 = fmaf(-wyCi, xB.y, hv[u].w);
            acc += fmaf(d0, d0, fmaf(d1, d1, fmaf(d2, d2, d3 * d3)));
        }
    }
    if (c1 & 3) {                    // masked tail chunk (wave-uniform)
        float inv[4];
        int   syo[4], sxo[4], sb[4], ok[4];
        float4 hv[4];
        #pragma unroll
        for (int u = 0; u < 4; u++) {
            int ee = nfull + u;
            ok[u] = (ee < c1);
            float2 mv = list[lbase + (ok[u] ? ee : c1 - 1)];
            inv[u] = mv.x;
            int sp = __builtin_amdgcn_readfirstlane(__float_as_int(mv.y));
            syo[u] = ( sp       & 15) << 6;
            sxo[u] = ((sp >> 4) & 15) << 6;
            sb[u]  = (sp >> 24) * CHB;
            hv[u] = *(const float4*)(hb + sb[u] + voff);
        }
        #pragma unroll
        for (int u = 0; u < 4; u++) {
            const float* ry = (const float*)(g8 + syo[u] + brr);
            const char*  rx = g8 + sxo[u] + bcc;
            float2 xA = *(const float2*)rx;
            float2 xB = *(const float2*)(rx + 8);
            float wy0 = ry[0], wy1 = ry[1];
            float wy0i = wy0 * inv[u];
            float wyCi = (wrap ? wy1 : wy0) * inv[u];
            float d0 = fmaf(-wy0i, xA.x, hv[u].x);
            float d1 = fmaf(-wy0i, xA.y, hv[u].y);
            float d2 = fmaf(-wyCi, xB.x, hv[u].z);
            float d3 = fmaf(-wyCi, xB.y, hv[u].w);
            float s  = fmaf(d0, d0, fmaf(d1, d1, fmaf(d2, d2, d3 * d3)));
            acc += ok[u] ? s : 0.f;
        }
    }

    // slow path: np >= 2 (avg ~2 entries)
    for (int e = c1; e < cT; e++) {
        float2 mv = list[lbase + e];
        float inv = mv.x;
        int sp = __builtin_amdgcn_readfirstlane(__float_as_int(mv.y));
        int sb = (sp >> 24) * CHB;
        float4 hv = *(const float4*)(hb + sb + voff);
        float f0 = 0.f, f1 = 0.f, f2 = 0.f, f3 = 0.f;
        #pragma unroll
        for (int q = 0; q < 3; q++) {
            int yo = ((sp >> (8 * q))     & 15) << 6;
            int xo = ((sp >> (8 * q + 4)) & 15) << 6;
            const float* ry = (const float*)(g8 + yo + brr);
            const char*  rx = g8 + xo + bcc;
            float2 xA = *(const float2*)rx;
            float2 xB = *(const float2*)(rx + 8);
            float wy0 = ry[0], wy1 = ry[1];
            float wyC = wrap ? wy1 : wy0;
            f0 = fmaf(wy0, xA.x, f0);
            f1 = fmaf(wy0, xA.y, f1);
            f2 = fmaf(wyC, xB.x, f2);
            f3 = fmaf(wyC, xB.y, f3);
        }
        float d0 = fmaf(-f0, inv, hv.x);
        float d1 = fmaf(-f1, inv, hv.y);
        float d2 = fmaf(-f2, inv, hv.z);
        float d3 = fmaf(-f3, inv, hv.w);
        acc += fmaf(d0, d0, fmaf(d1, d1, fmaf(d2, d2, d3 * d3)));
    }

    acc = lv ? acc : 0.f;            // single lane-mask application

    // ---- reduce ----
    #pragma unroll
    for (int off = 32; off > 0; off >>= 1) acc += __shfl_down(acc, off);
    if (lane == 0) wred[w] = acc;
    __syncthreads();
    if (tid == 0) {
        float2 pr;
        float s = 0.f, vs = 0.f;
        #pragma unroll
        for (int q = 0; q < BPB; q++) { s += wred[q]; vs += wvs[q]; }
        pr.x = s; pr.y = vs;
        partials[blockIdx.x] = pr;
    }
}

__global__ __launch_bounds__(256) void finalize_kernel(
    const float4* __restrict__ partials4, float* __restrict__ out)
{
    __shared__ float w1[4], w2[4];
    int tid = threadIdx.x;
    float4 p0 = partials4[tid];           // 512 float4 == 1024 float2 partials
    float4 p1 = partials4[tid + 256];
    float s  = (p0.x + p0.z) + (p1.x + p1.z);
    float vs = (p0.y + p0.w) + (p1.y + p1.w);
    #pragma unroll
    for (int off = 32; off > 0; off >>= 1) {
        s  += __shfl_down(s, off);
        vs += __shfl_down(vs, off);
    }
    if ((tid & 63) == 0) { w1[tid >> 6] = s; w2[tid >> 6] = vs; }
    __syncthreads();
    if (tid == 0) {
        float stot = w1[0] + w1[1] + w1[2] + w1[3];
        float vtot = w2[0] + w2[1] + w2[2] + w2[3];
        out[0] = stot / (vtot * 0.5f);
    }
}

extern "C" void kernel_launch(void* const* d_in, const int* in_sizes, int n_in,
                              void* d_out, int out_size, void* d_ws, size_t ws_size,
                              hipStream_t stream) {
    // inputs: 0=os (UNUSED), 1=h [B,18,14,14] f32, 2=t [B,14,2] f32, 3=v [B,14,2] i32
    const float* h = (const float*)d_in[1];
    const float* t = (const float*)d_in[2];
    const int*   v = (const int*)d_in[3];
    float2* partials = (float2*)d_ws;   // NBLK float2

    mse_partial_kernel<<<NBLK, 512, 0, stream>>>(h, t, v, partials);
    finalize_kernel<<<1, 256, 0, stream>>>((const float4*)partials, (float*)d_out);
}